// Round 4
// baseline (928.361 us; speedup 1.0000x reference)
//
#include <hip/hip_runtime.h>
#include <math.h>

// Problem constants (from reference)
#define NB   4
#define NC   4
#define NF   257
#define NFRM 2000
#define PLANE (NB*NC*NF*NFRM)   // 8,224,000
#define EPS  1e-3f
#define INV_FN (1.0f/514000.0f) // 1/(NF*NFRM)

#define RFC  29                 // k_r frequency chunks
#define RFP  9                  // f per chunk (29*9=261 >= 257)
#define UT   512                // k_u threads
#define UK   4                  // contiguous frames per thread (500*4 = 2000)

__device__ __forceinline__ float2 cmulf(float2 a, float2 b) {
  return make_float2(a.x*b.x - a.y*b.y, a.x*b.y + a.y*b.x);
}

// zero rsum (32000) + gpart (48)
__global__ __launch_bounds__(256)
void k_zero(float* __restrict__ rsum, float* __restrict__ gpart) {
  int idx = blockIdx.x*256 + threadIdx.x;
  if (idx < 32000) rsum[idx] = 0.f;
  else if (idx < 32048) gpart[idx-32000] = 0.f;
}

// r-pass: rsum[b,c,n] += sum over f-chunk of |X|^2 (atomic), gpart[bc] += total
__global__ __launch_bounds__(256)
void k_r(const float* __restrict__ Xr, const float* __restrict__ Xi,
         float* __restrict__ rsum, float* __restrict__ gpart)
{
  const int tid = threadIdx.x;
  const int q   = blockIdx.x*256 + tid;   // float4 index over n, 500 valid
  const int fc  = blockIdx.y;
  const int bc  = blockIdx.z;
  float4 s4 = make_float4(0.f,0.f,0.f,0.f);
  if (q < 500) {
    const int f0 = fc*RFP;
    const int f1 = (f0+RFP < NF) ? (f0+RFP) : NF;
    const float4* r4 = (const float4*)(Xr + (size_t)(bc*NF+f0)*NFRM) + q;
    const float4* i4 = (const float4*)(Xi + (size_t)(bc*NF+f0)*NFRM) + q;
    for (int f=f0; f<f1; ++f) {
      float4 a = *r4, b2 = *i4;
      s4.x += a.x*a.x + b2.x*b2.x;
      s4.y += a.y*a.y + b2.y*b2.y;
      s4.z += a.z*a.z + b2.z*b2.z;
      s4.w += a.w*a.w + b2.w*b2.w;
      r4 += 500; i4 += 500;
    }
    float* rp = rsum + bc*NFRM + q*4;
    atomicAdd(rp+0, s4.x); atomicAdd(rp+1, s4.y);
    atomicAdd(rp+2, s4.z); atomicAdd(rp+3, s4.w);
  }
  float t = s4.x+s4.y+s4.z+s4.w;
  #pragma unroll
  for (int o=32;o;o>>=1) t += __shfl_down(t, o);
  __shared__ float wred[4];
  if ((tid & 63) == 0) wred[tid>>6] = t;
  __syncthreads();
  if (tid == 0) atomicAdd(&gpart[bc], wred[0]+wred[1]+wred[2]+wred[3]);
}

// weights kernel: w0g[b,c,n] = g[b,c] / max(2*sqrt(rsum), 1e-5); re-zero rsum
__global__ __launch_bounds__(256)
void k_w(float* __restrict__ rsum, const float* __restrict__ gpart,
         float* __restrict__ w0g)
{
  int idx = blockIdx.x*256 + threadIdx.x;   // 125*256 = 32000 exact
  int bc  = idx / NFRM;
  float g = fmaxf(gpart[bc]*INV_FN, EPS);
  float r = rsum[idx];
  w0g[idx] = g / fmaxf(2.0f*sqrtf(r), 1e-5f);
  rsum[idx] = 0.f;
}

// single-barrier 12-value block reduction, parity-double-buffered (8 waves)
#define REDUCE12(P)                                                       \
  {                                                                       \
    _Pragma("unroll")                                                     \
    for (int o=32;o;o>>=1) {                                              \
      _Pragma("unroll")                                                   \
      for (int i=0;i<12;i++) acc[i] += __shfl_down(acc[i], o);            \
    }                                                                     \
    if ((tid & 63) == 0) {                                                \
      const int wid = tid >> 6;                                           \
      _Pragma("unroll")                                                   \
      for (int i=0;i<12;i++) wpart[P][wid][i] = acc[i];                   \
    }                                                                     \
    __syncthreads();                                                      \
    _Pragma("unroll")                                                     \
    for (int i=0;i<12;i++) vsum[i] = 0.f;                                 \
    _Pragma("unroll")                                                     \
    for (int w=0;w<8;w++) {                                               \
      const float4* wp = (const float4*)wpart[P][w];                      \
      float4 p0 = wp[0], p1 = wp[1], p2 = wp[2];                          \
      vsum[0]+=p0.x; vsum[1]+=p0.y; vsum[2] +=p0.z; vsum[3] +=p0.w;       \
      vsum[4]+=p1.x; vsum[5]+=p1.y; vsum[6] +=p1.z; vsum[7] +=p1.w;       \
      vsum[8]+=p2.x; vsum[9]+=p2.y; vsum[10]+=p2.z; vsum[11]+=p2.w;       \
    }                                                                     \
  }

// Per-(b,f) update kernel. 512 threads, 4 CONTIGUOUS frames each.
// __launch_bounds__(512,2): 2 blocks/CU -> VGPR cap 128 (need ~110, no spill).
template<bool FIRST, bool LAST>
__global__ __launch_bounds__(UT, 2)
void k_u(const float* Xsr, const float* Xsi,                 // current X source
         const float* __restrict__ Xor_, const float* __restrict__ Xoi_, // original (taps)
         float* Xdr, float* Xdi,                             // dest (may alias src)
         const float* __restrict__ w0gbuf,
         const float* __restrict__ gpart,
         float2* __restrict__ Wg)
{
  __shared__ __align__(16) float wpart[2][8][16];
  __shared__ float2 Wl[NC][NC];
  __shared__ float2 avec[NC];

  const int tid = threadIdx.x;
  const int f = blockIdx.x;
  const int b = blockIdx.y;
  const bool valid = tid < 500;
  const int n0 = tid*UK;                    // first frame owned
  const float norm = 1.0f/(float)NFRM;

  float igs[NC];
  #pragma unroll
  for (int c=0;c<NC;c++) {
    float g = fmaxf(gpart[b*NC+c]*INV_FN, EPS);
    igs[c] = 1.0f/sqrtf(g);
  }

  // load + rescale X (one float4 per plane per channel)
  float2 x[NC][UK];
  #pragma unroll
  for (int c=0;c<NC;c++) {
    #pragma unroll
    for (int k=0;k<UK;k++) x[c][k] = make_float2(0.f,0.f);
    if (valid) {
      const size_t rb = ((size_t)(b*NC+c)*NF + f)*NFRM;
      float4 r0 = *(const float4*)(Xsr + rb + n0);
      float4 i0 = *(const float4*)(Xsi + rb + n0);
      x[c][0] = make_float2(r0.x*igs[c], i0.x*igs[c]);
      x[c][1] = make_float2(r0.y*igs[c], i0.y*igs[c]);
      x[c][2] = make_float2(r0.z*igs[c], i0.z*igs[c]);
      x[c][3] = make_float2(r0.w*igs[c], i0.w*igs[c]);
    }
  }
  // precomputed weights (one float4 per channel)
  float w0g[NC][UK];
  #pragma unroll
  for (int c=0;c<NC;c++) {
    #pragma unroll
    for (int k=0;k<UK;k++) w0g[c][k] = 0.f;
    if (valid) {
      float4 w4 = *(const float4*)(w0gbuf + (b*NC+c)*NFRM + n0);
      w0g[c][0]=w4.x; w0g[c][1]=w4.y; w0g[c][2]=w4.z; w0g[c][3]=w4.w;
    }
  }
  // W load/init + rescale (wave 0 only)
  if (tid < 16) {
    const int c = tid>>2, d = tid&3;
    float2 w;
    if (FIRST) w = make_float2((c==d)?1.f:0.f, 0.f);
    else       w = Wg[(size_t)(b*NF+f)*16 + tid];
    Wl[c][d] = make_float2(w.x*igs[c], w.y*igs[c]);
  }

  // ---------- type-1 sweeps (fully unrolled: x[s] register-indexed) ----------
  #pragma unroll
  for (int s=0;s<NC;s++) {
    float acc[12];
    #pragma unroll
    for (int i=0;i<12;i++) acc[i] = 0.f;
    #pragma unroll
    for (int k=0;k<UK;k++) {
      float2 xs = x[s][k];
      float m = xs.x*xs.x + xs.y*xs.y;
      #pragma unroll
      for (int c=0;c<NC;c++) {
        float2 xc = x[c][k];
        float w = w0g[c][k];
        acc[c]   += w*(xc.x*xs.x + xc.y*xs.y);
        acc[4+c] += w*(xc.y*xs.x - xc.x*xs.y);
        acc[8+c] += w*m;
      }
    }
    float vsum[12];
    REDUCE12(s&1);
    float2 v[NC];
    #pragma unroll
    for (int c=0;c<NC;c++) {
      float dn = fmaxf(vsum[8+c]*norm, EPS);
      v[c] = make_float2(vsum[c]*norm/dn, vsum[4+c]*norm/dn);
    }
    v[s] = make_float2(1.0f - 1.0f/sqrtf(fmaxf(vsum[8+s]*norm, EPS)), 0.f);
    #pragma unroll
    for (int k=0;k<UK;k++) {
      float2 xs = x[s][k];
      #pragma unroll
      for (int c=0;c<NC;c++) {
        float2 xv = x[c][k];
        xv.x -= v[c].x*xs.x - v[c].y*xs.y;
        xv.y -= v[c].x*xs.y + v[c].y*xs.x;
        x[c][k] = xv;
      }
    }
    if (tid < 16) {
      const int c = tid>>2, d = tid&3;
      float2 wsd = Wl[s][d];
      float2 wv = Wl[c][d];
      wv.x -= v[c].x*wsd.x - v[c].y*wsd.y;
      wv.y -= v[c].x*wsd.y + v[c].y*wsd.x;
      Wl[c][d] = wv;
    }
  }

  // ---------- type-2 sweeps (s-loop NOT unrolled: only addresses depend on s) ----------
  #pragma unroll 1
  for (int s=0;s<NC;s++) {
    const size_t ob = ((size_t)(b*NC+s)*NF + f)*NFRM;
    // aligned 8-float window [n0-4, n0+4) of the tap plane, shared by both taps
    float winr[8], wini[8];
    {
      float4 m1r=make_float4(0,0,0,0), m1i=m1r, p0r=m1r, p0i=m1r;
      if (valid) {
        const float* tp = Xor_ + ob + n0;
        const float* ti = Xoi_ + ob + n0;
        if (tid > 0) { m1r = *(const float4*)(tp-4); m1i = *(const float4*)(ti-4); }
        p0r = *(const float4*)tp;  p0i = *(const float4*)ti;
      }
      winr[0]=m1r.x; winr[1]=m1r.y; winr[2]=m1r.z; winr[3]=m1r.w;
      winr[4]=p0r.x; winr[5]=p0r.y; winr[6]=p0r.z; winr[7]=p0r.w;
      wini[0]=m1i.x; wini[1]=m1i.y; wini[2]=m1i.z; wini[3]=m1i.w;
      wini[4]=p0i.x; wini[5]=p0i.y; wini[6]=p0i.z; wini[7]=p0i.w;
    }
    #pragma unroll
    for (int t2=0;t2<2;t2++) {
      float acc[12];
      #pragma unroll
      for (int i=0;i<12;i++) acc[i] = 0.f;
      #pragma unroll
      for (int k=0;k<UK;k++) {
        float2 xs = make_float2(winr[k+1+t2], wini[k+1+t2]);  // frame n0+k+t2-3
        float m = xs.x*xs.x + xs.y*xs.y;
        #pragma unroll
        for (int c=0;c<NC;c++) {
          float2 xc = x[c][k];
          float w = w0g[c][k];
          acc[c]   += w*(xc.x*xs.x + xc.y*xs.y);
          acc[4+c] += w*(xc.y*xs.x - xc.x*xs.y);
          acc[8+c] += w*m;
        }
      }
      float vsum[12];
      REDUCE12(t2&1);   // type-1 ended on parity 1; t2 alternates 0,1,0,1,...
      float2 v[NC];
      #pragma unroll
      for (int c=0;c<NC;c++) {
        float dn = fmaxf(vsum[8+c]*norm, EPS);
        v[c] = make_float2(vsum[c]*norm/dn, vsum[4+c]*norm/dn);
      }
      #pragma unroll
      for (int k=0;k<UK;k++) {
        float2 xs = make_float2(winr[k+1+t2], wini[k+1+t2]);
        #pragma unroll
        for (int c=0;c<NC;c++) {
          float2 xv = x[c][k];
          xv.x -= v[c].x*xs.x - v[c].y*xs.y;
          xv.y -= v[c].x*xs.y + v[c].y*xs.x;
          x[c][k] = xv;
        }
      }
    }
  }

  // ---------- epilogue ----------
  if (LAST) {
    if (tid == 0) {
      float2 A[4][4], bb[4], xv[4];
      for (int i=0;i<4;i++)
        for (int j=0;j<4;j++)
          A[i][j] = Wl[j][i];
      for (int i=0;i<4;i++) A[i][i].x += 1e-6f;
      bb[0] = make_float2(1.f,0.f);
      bb[1] = make_float2(0.f,0.f);
      bb[2] = make_float2(0.f,0.f);
      bb[3] = make_float2(0.f,0.f);
      for (int col=0; col<4; ++col) {
        int p = col;
        float best = A[col][col].x*A[col][col].x + A[col][col].y*A[col][col].y;
        for (int r=col+1;r<4;r++) {
          float m = A[r][col].x*A[r][col].x + A[r][col].y*A[r][col].y;
          if (m > best) { best = m; p = r; }
        }
        if (p != col) {
          for (int j=0;j<4;j++) { float2 ts = A[col][j]; A[col][j] = A[p][j]; A[p][j] = ts; }
          float2 ts = bb[col]; bb[col] = bb[p]; bb[p] = ts;
        }
        float2 piv = A[col][col];
        float ib = 1.0f / (piv.x*piv.x + piv.y*piv.y);
        float2 inv = make_float2(piv.x*ib, -piv.y*ib);
        for (int r=col+1;r<4;r++) {
          float2 fac = cmulf(A[r][col], inv);
          for (int j=col;j<4;j++) {
            float2 pr = cmulf(fac, A[col][j]);
            A[r][j].x -= pr.x; A[r][j].y -= pr.y;
          }
          float2 pb = cmulf(fac, bb[col]);
          bb[r].x -= pb.x; bb[r].y -= pb.y;
        }
      }
      for (int r=3;r>=0;r--) {
        float2 t = bb[r];
        for (int j=r+1;j<4;j++) {
          float2 pr = cmulf(A[r][j], xv[j]);
          t.x -= pr.x; t.y -= pr.y;
        }
        float2 d = A[r][r];
        float ib = 1.0f/(d.x*d.x + d.y*d.y);
        xv[r] = cmulf(t, make_float2(d.x*ib, -d.y*ib));
      }
      for (int c=0;c<4;c++) avec[c] = xv[c];
    }
    __syncthreads();
    if (valid) {
      #pragma unroll
      for (int c=0;c<NC;c++) {
        const size_t rb = ((size_t)(b*NC+c)*NF + f)*NFRM;
        float2 a = avec[c];
        float2 y0 = cmulf(a, x[c][0]), y1 = cmulf(a, x[c][1]);
        float2 y2 = cmulf(a, x[c][2]), y3 = cmulf(a, x[c][3]);
        *(float4*)(Xdr + rb + n0) = make_float4(y0.x,y1.x,y2.x,y3.x);
        *(float4*)(Xdi + rb + n0) = make_float4(y0.y,y1.y,y2.y,y3.y);
      }
    }
  } else {
    if (valid) {
      #pragma unroll
      for (int c=0;c<NC;c++) {
        const size_t rb = ((size_t)(b*NC+c)*NF + f)*NFRM;
        *(float4*)(Xdr + rb + n0) = make_float4(x[c][0].x,x[c][1].x,x[c][2].x,x[c][3].x);
        *(float4*)(Xdi + rb + n0) = make_float4(x[c][0].y,x[c][1].y,x[c][2].y,x[c][3].y);
      }
    }
    if (tid < 16) Wg[(size_t)(b*NF+f)*16 + tid] = Wl[tid>>2][tid&3];
  }
}

extern "C" void kernel_launch(void* const* d_in, const int* in_sizes, int n_in,
                              void* d_out, int out_size, void* d_ws, size_t ws_size,
                              hipStream_t stream)
{
  (void)in_sizes; (void)n_in; (void)out_size; (void)ws_size;
  const float* xr_in = (const float*)d_in[0];
  const float* xi_in = (const float*)d_in[1];
  float* outr = (float*)d_out;
  float* outi = outr + PLANE;

  char*  ws    = (char*)d_ws;
  float* rsum  = (float*)ws;                       // 32000 floats = 128 KB
  float* w0g   = (float*)(ws + 128000);            // 32000 floats = 128 KB
  float* gpart = (float*)(ws + 256000);            // 48 floats
  float2* Wg   = (float2*)(ws + 256000 + 256);     // 1028*16 float2 = 131,584 B

  dim3 grR(2, RFC, NB*NC);    // 928 blocks
  dim3 grU(NF, NB);           // 1028 blocks

  k_zero<<<126, 256, 0, stream>>>(rsum, gpart);

  // iteration 0 (X = original input)
  k_r<<<grR, 256, 0, stream>>>(xr_in, xi_in, rsum, gpart + 0);
  k_w<<<125, 256, 0, stream>>>(rsum, gpart + 0, w0g);
  k_u<true,false><<<grU, UT, 0, stream>>>(xr_in, xi_in, xr_in, xi_in,
                                          outr, outi, w0g, gpart + 0, Wg);
  // iteration 1
  k_r<<<grR, 256, 0, stream>>>(outr, outi, rsum, gpart + 16);
  k_w<<<125, 256, 0, stream>>>(rsum, gpart + 16, w0g);
  k_u<false,false><<<grU, UT, 0, stream>>>(outr, outi, xr_in, xi_in,
                                           outr, outi, w0g, gpart + 16, Wg);
  // iteration 2 + projection_back
  k_r<<<grR, 256, 0, stream>>>(outr, outi, rsum, gpart + 32);
  k_w<<<125, 256, 0, stream>>>(rsum, gpart + 32, w0g);
  k_u<false,true><<<grU, UT, 0, stream>>>(outr, outi, xr_in, xi_in,
                                          outr, outi, w0g, gpart + 32, Wg);
}

// Round 5
// 541.608 us; speedup vs baseline: 1.7141x; 1.7141x over previous
//
#include <hip/hip_runtime.h>
#include <math.h>

// Problem constants (from reference)
#define NB   4
#define NC   4
#define NF   257
#define NFRM 2000
#define PLANE (NB*NC*NF*NFRM)   // 8,224,000
#define EPS  1e-3f
#define INV_FN (1.0f/514000.0f) // 1/(NF*NFRM)

#define RFC  29                 // k_r frequency chunks
#define RFP  9                  // f per chunk (29*9=261 >= 257)
#define UT   512                // k_u threads
#define UK   4                  // contiguous frames per thread (500*4 = 2000)

__device__ __forceinline__ float2 cmulf(float2 a, float2 b) {
  return make_float2(a.x*b.x - a.y*b.y, a.x*b.y + a.y*b.x);
}

// DPP wave-64 sum: after this, lane 63 of each wave holds the full wave sum.
// row_shr:1,2,4,8 then row_bcast:15, row_bcast:31. All VALU-pipe, no LDS.
#define DPP_STAGE(x, CTRL)                                                \
  x += __int_as_float(__builtin_amdgcn_update_dpp(                        \
        0, __float_as_int(x), CTRL, 0xf, 0xf, true))

__device__ __forceinline__ void wave_reduce12(float* acc) {
  #pragma unroll
  for (int i=0;i<12;i++) {
    float xv = acc[i];
    DPP_STAGE(xv, 0x111);   // row_shr:1
    DPP_STAGE(xv, 0x112);   // row_shr:2
    DPP_STAGE(xv, 0x114);   // row_shr:4
    DPP_STAGE(xv, 0x118);   // row_shr:8
    DPP_STAGE(xv, 0x142);   // row_bcast:15
    DPP_STAGE(xv, 0x143);   // row_bcast:31
    acc[i] = xv;            // lane 63: wave total
  }
}

// zero rsum (32000) + gpart (48)
__global__ __launch_bounds__(256)
void k_zero(float* __restrict__ rsum, float* __restrict__ gpart) {
  int idx = blockIdx.x*256 + threadIdx.x;
  if (idx < 32000) rsum[idx] = 0.f;
  else if (idx < 32048) gpart[idx-32000] = 0.f;
}

// r-pass: rsum[b,c,n] += sum over f-chunk of |X|^2 (atomic), gpart[bc] += total
__global__ __launch_bounds__(256)
void k_r(const float* __restrict__ Xr, const float* __restrict__ Xi,
         float* __restrict__ rsum, float* __restrict__ gpart)
{
  const int tid = threadIdx.x;
  const int q   = blockIdx.x*256 + tid;   // float4 index over n, 500 valid
  const int fc  = blockIdx.y;
  const int bc  = blockIdx.z;
  float4 s4 = make_float4(0.f,0.f,0.f,0.f);
  if (q < 500) {
    const int f0 = fc*RFP;
    const int f1 = (f0+RFP < NF) ? (f0+RFP) : NF;
    const float4* r4 = (const float4*)(Xr + (size_t)(bc*NF+f0)*NFRM) + q;
    const float4* i4 = (const float4*)(Xi + (size_t)(bc*NF+f0)*NFRM) + q;
    for (int f=f0; f<f1; ++f) {
      float4 a = *r4, b2 = *i4;
      s4.x += a.x*a.x + b2.x*b2.x;
      s4.y += a.y*a.y + b2.y*b2.y;
      s4.z += a.z*a.z + b2.z*b2.z;
      s4.w += a.w*a.w + b2.w*b2.w;
      r4 += 500; i4 += 500;
    }
    float* rp = rsum + bc*NFRM + q*4;
    atomicAdd(rp+0, s4.x); atomicAdd(rp+1, s4.y);
    atomicAdd(rp+2, s4.z); atomicAdd(rp+3, s4.w);
  }
  float t = s4.x+s4.y+s4.z+s4.w;
  #pragma unroll
  for (int o=32;o;o>>=1) t += __shfl_down(t, o);
  __shared__ float wred[4];
  if ((tid & 63) == 0) wred[tid>>6] = t;
  __syncthreads();
  if (tid == 0) atomicAdd(&gpart[bc], wred[0]+wred[1]+wred[2]+wred[3]);
}

// weights kernel: w0g[b,c,n] = g[b,c] / max(2*sqrt(rsum), 1e-5); re-zero rsum
__global__ __launch_bounds__(256)
void k_w(float* __restrict__ rsum, const float* __restrict__ gpart,
         float* __restrict__ w0g)
{
  int idx = blockIdx.x*256 + threadIdx.x;   // 125*256 = 32000 exact
  int bc  = idx / NFRM;
  float g = fmaxf(gpart[bc]*INV_FN, EPS);
  float r = rsum[idx];
  float s = fmaxf(2.0f*sqrtf(r), 1e-5f);
  w0g[idx] = g * __builtin_amdgcn_rcpf(s);
  rsum[idx] = 0.f;
}

// Block reduce: DPP wave-reduce (VALU), lane-63 b128 writes, 12-thread cross-wave
// sum, broadcast b128 re-read. 2 barriers, ~60 LDS-pipe ops total.
#define REDUCE12()                                                        \
  {                                                                       \
    wave_reduce12(acc);                                                   \
    if ((tid & 63) == 63) {                                               \
      const int wid = tid >> 6;                                           \
      *(float4*)&wpart[wid][0] = make_float4(acc[0],acc[1],acc[2],acc[3]);\
      *(float4*)&wpart[wid][4] = make_float4(acc[4],acc[5],acc[6],acc[7]);\
      *(float4*)&wpart[wid][8] = make_float4(acc[8],acc[9],acc[10],acc[11]);\
    }                                                                     \
    __syncthreads();                                                      \
    if (tid < 12) {                                                       \
      float t = 0.f;                                                      \
      _Pragma("unroll")                                                   \
      for (int w=0;w<8;w++) t += wpart[w][tid];                           \
      vredL[tid] = t;                                                     \
    }                                                                     \
    __syncthreads();                                                      \
    {                                                                     \
      float4 vv0 = *(const float4*)&vredL[0];                             \
      float4 vv1 = *(const float4*)&vredL[4];                             \
      float4 vv2 = *(const float4*)&vredL[8];                             \
      vsum[0]=vv0.x; vsum[1]=vv0.y; vsum[2] =vv0.z; vsum[3] =vv0.w;       \
      vsum[4]=vv1.x; vsum[5]=vv1.y; vsum[6] =vv1.z; vsum[7] =vv1.w;       \
      vsum[8]=vv2.x; vsum[9]=vv2.y; vsum[10]=vv2.z; vsum[11]=vv2.w;       \
    }                                                                     \
  }

// Per-(b,f) update kernel. 512 threads, 4 CONTIGUOUS frames each, 2 blocks/CU.
template<bool FIRST, bool LAST>
__global__ __launch_bounds__(UT, 2)
void k_u(const float* Xsr, const float* Xsi,                 // current X source
         const float* __restrict__ Xor_, const float* __restrict__ Xoi_, // original (taps)
         float* Xdr, float* Xdi,                             // dest (may alias src)
         const float* __restrict__ w0gbuf,
         const float* __restrict__ gpart,
         float2* __restrict__ Wg)
{
  __shared__ __align__(16) float wpart[8][16];
  __shared__ __align__(16) float vredL[16];
  __shared__ float2 Wl[NC][NC];
  __shared__ float2 avec[NC];

  const int tid = threadIdx.x;
  const int f = blockIdx.x;
  const int b = blockIdx.y;
  const bool valid = tid < 500;
  const int n0 = tid*UK;                    // first frame owned
  const float norm = 1.0f/(float)NFRM;

  float igs[NC];
  #pragma unroll
  for (int c=0;c<NC;c++) {
    float g = fmaxf(gpart[b*NC+c]*INV_FN, EPS);
    igs[c] = __builtin_amdgcn_rsqf(g);
  }

  // load + rescale X (one float4 per plane per channel)
  float2 x[NC][UK];
  #pragma unroll
  for (int c=0;c<NC;c++) {
    #pragma unroll
    for (int k=0;k<UK;k++) x[c][k] = make_float2(0.f,0.f);
    if (valid) {
      const size_t rb = ((size_t)(b*NC+c)*NF + f)*NFRM;
      float4 r0 = *(const float4*)(Xsr + rb + n0);
      float4 i0 = *(const float4*)(Xsi + rb + n0);
      x[c][0] = make_float2(r0.x*igs[c], i0.x*igs[c]);
      x[c][1] = make_float2(r0.y*igs[c], i0.y*igs[c]);
      x[c][2] = make_float2(r0.z*igs[c], i0.z*igs[c]);
      x[c][3] = make_float2(r0.w*igs[c], i0.w*igs[c]);
    }
  }
  // precomputed weights (one float4 per channel)
  float w0g[NC][UK];
  #pragma unroll
  for (int c=0;c<NC;c++) {
    #pragma unroll
    for (int k=0;k<UK;k++) w0g[c][k] = 0.f;
    if (valid) {
      float4 w4 = *(const float4*)(w0gbuf + (b*NC+c)*NFRM + n0);
      w0g[c][0]=w4.x; w0g[c][1]=w4.y; w0g[c][2]=w4.z; w0g[c][3]=w4.w;
    }
  }
  // W load/init + rescale (wave 0 only)
  if (tid < 16) {
    const int c = tid>>2, d = tid&3;
    float2 w;
    if (FIRST) w = make_float2((c==d)?1.f:0.f, 0.f);
    else       w = Wg[(size_t)(b*NF+f)*16 + tid];
    Wl[c][d] = make_float2(w.x*igs[c], w.y*igs[c]);
  }

  // ---------- type-1 sweeps (fully unrolled: x[s] register-indexed) ----------
  #pragma unroll
  for (int s=0;s<NC;s++) {
    float acc[12];
    #pragma unroll
    for (int i=0;i<12;i++) acc[i] = 0.f;
    #pragma unroll
    for (int k=0;k<UK;k++) {
      float2 xs = x[s][k];
      float m = xs.x*xs.x + xs.y*xs.y;
      #pragma unroll
      for (int c=0;c<NC;c++) {
        float2 xc = x[c][k];
        float w = w0g[c][k];
        acc[c]   += w*(xc.x*xs.x + xc.y*xs.y);
        acc[4+c] += w*(xc.y*xs.x - xc.x*xs.y);
        acc[8+c] += w*m;
      }
    }
    float vsum[12];
    REDUCE12();
    float2 v[NC];
    #pragma unroll
    for (int c=0;c<NC;c++) {
      float dn = fmaxf(vsum[8+c]*norm, EPS);
      float rc = __builtin_amdgcn_rcpf(dn) * norm;
      v[c] = make_float2(vsum[c]*rc, vsum[4+c]*rc);
    }
    v[s] = make_float2(1.0f - __builtin_amdgcn_rsqf(fmaxf(vsum[8+s]*norm, EPS)), 0.f);
    #pragma unroll
    for (int k=0;k<UK;k++) {
      float2 xs = x[s][k];
      #pragma unroll
      for (int c=0;c<NC;c++) {
        float2 xv = x[c][k];
        xv.x -= v[c].x*xs.x - v[c].y*xs.y;
        xv.y -= v[c].x*xs.y + v[c].y*xs.x;
        x[c][k] = xv;
      }
    }
    if (tid < 16) {
      const int c = tid>>2, d = tid&3;
      float2 wsd = Wl[s][d];
      float2 wv = Wl[c][d];
      wv.x -= v[c].x*wsd.x - v[c].y*wsd.y;
      wv.y -= v[c].x*wsd.y + v[c].y*wsd.x;
      Wl[c][d] = wv;
    }
  }

  // ---------- type-2 sweeps: s-loop kept rolled, tap windows prefetched 1 ahead ----------
  // window for source s: 8 floats [n0-4, n0+4) per component
  float winr[8], wini[8], nxtr[8], nxti[8];
  {
    const size_t ob = ((size_t)(b*NC+0)*NF + f)*NFRM;
    float4 m1r=make_float4(0,0,0,0), m1i=m1r, p0r=m1r, p0i=m1r;
    if (valid) {
      const float* tp = Xor_ + ob + n0;
      const float* ti = Xoi_ + ob + n0;
      if (tid > 0) { m1r = *(const float4*)(tp-4); m1i = *(const float4*)(ti-4); }
      p0r = *(const float4*)tp;  p0i = *(const float4*)ti;
    }
    winr[0]=m1r.x; winr[1]=m1r.y; winr[2]=m1r.z; winr[3]=m1r.w;
    winr[4]=p0r.x; winr[5]=p0r.y; winr[6]=p0r.z; winr[7]=p0r.w;
    wini[0]=m1i.x; wini[1]=m1i.y; wini[2]=m1i.z; wini[3]=m1i.w;
    wini[4]=p0i.x; wini[5]=p0i.y; wini[6]=p0i.z; wini[7]=p0i.w;
  }
  #pragma unroll 1
  for (int s=0;s<NC;s++) {
    // prefetch next source's window (address data-independent) before computing
    if (s < NC-1) {
      const size_t ob = ((size_t)(b*NC+s+1)*NF + f)*NFRM;
      float4 m1r=make_float4(0,0,0,0), m1i=m1r, p0r=m1r, p0i=m1r;
      if (valid) {
        const float* tp = Xor_ + ob + n0;
        const float* ti = Xoi_ + ob + n0;
        if (tid > 0) { m1r = *(const float4*)(tp-4); m1i = *(const float4*)(ti-4); }
        p0r = *(const float4*)tp;  p0i = *(const float4*)ti;
      }
      nxtr[0]=m1r.x; nxtr[1]=m1r.y; nxtr[2]=m1r.z; nxtr[3]=m1r.w;
      nxtr[4]=p0r.x; nxtr[5]=p0r.y; nxtr[6]=p0r.z; nxtr[7]=p0r.w;
      nxti[0]=m1i.x; nxti[1]=m1i.y; nxti[2]=m1i.z; nxti[3]=m1i.w;
      nxti[4]=p0i.x; nxti[5]=p0i.y; nxti[6]=p0i.z; nxti[7]=p0i.w;
    }
    #pragma unroll
    for (int t2=0;t2<2;t2++) {
      float acc[12];
      #pragma unroll
      for (int i=0;i<12;i++) acc[i] = 0.f;
      #pragma unroll
      for (int k=0;k<UK;k++) {
        float2 xs = make_float2(winr[k+1+t2], wini[k+1+t2]);  // frame n0+k+t2-3
        float m = xs.x*xs.x + xs.y*xs.y;
        #pragma unroll
        for (int c=0;c<NC;c++) {
          float2 xc = x[c][k];
          float w = w0g[c][k];
          acc[c]   += w*(xc.x*xs.x + xc.y*xs.y);
          acc[4+c] += w*(xc.y*xs.x - xc.x*xs.y);
          acc[8+c] += w*m;
        }
      }
      float vsum[12];
      REDUCE12();
      float2 v[NC];
      #pragma unroll
      for (int c=0;c<NC;c++) {
        float dn = fmaxf(vsum[8+c]*norm, EPS);
        float rc = __builtin_amdgcn_rcpf(dn) * norm;
        v[c] = make_float2(vsum[c]*rc, vsum[4+c]*rc);
      }
      #pragma unroll
      for (int k=0;k<UK;k++) {
        float2 xs = make_float2(winr[k+1+t2], wini[k+1+t2]);
        #pragma unroll
        for (int c=0;c<NC;c++) {
          float2 xv = x[c][k];
          xv.x -= v[c].x*xs.x - v[c].y*xs.y;
          xv.y -= v[c].x*xs.y + v[c].y*xs.x;
          x[c][k] = xv;
        }
      }
    }
    #pragma unroll
    for (int j=0;j<8;j++) { winr[j]=nxtr[j]; wini[j]=nxti[j]; }
  }

  // ---------- epilogue ----------
  if (LAST) {
    if (tid == 0) {
      float2 A[4][4], bb[4], xv[4];
      for (int i=0;i<4;i++)
        for (int j=0;j<4;j++)
          A[i][j] = Wl[j][i];
      for (int i=0;i<4;i++) A[i][i].x += 1e-6f;
      bb[0] = make_float2(1.f,0.f);
      bb[1] = make_float2(0.f,0.f);
      bb[2] = make_float2(0.f,0.f);
      bb[3] = make_float2(0.f,0.f);
      for (int col=0; col<4; ++col) {
        int p = col;
        float best = A[col][col].x*A[col][col].x + A[col][col].y*A[col][col].y;
        for (int r=col+1;r<4;r++) {
          float m = A[r][col].x*A[r][col].x + A[r][col].y*A[r][col].y;
          if (m > best) { best = m; p = r; }
        }
        if (p != col) {
          for (int j=0;j<4;j++) { float2 ts = A[col][j]; A[col][j] = A[p][j]; A[p][j] = ts; }
          float2 ts = bb[col]; bb[col] = bb[p]; bb[p] = ts;
        }
        float2 piv = A[col][col];
        float ib = 1.0f / (piv.x*piv.x + piv.y*piv.y);
        float2 inv = make_float2(piv.x*ib, -piv.y*ib);
        for (int r=col+1;r<4;r++) {
          float2 fac = cmulf(A[r][col], inv);
          for (int j=col;j<4;j++) {
            float2 pr = cmulf(fac, A[col][j]);
            A[r][j].x -= pr.x; A[r][j].y -= pr.y;
          }
          float2 pb = cmulf(fac, bb[col]);
          bb[r].x -= pb.x; bb[r].y -= pb.y;
        }
      }
      for (int r=3;r>=0;r--) {
        float2 t = bb[r];
        for (int j=r+1;j<4;j++) {
          float2 pr = cmulf(A[r][j], xv[j]);
          t.x -= pr.x; t.y -= pr.y;
        }
        float2 d = A[r][r];
        float ib = 1.0f/(d.x*d.x + d.y*d.y);
        xv[r] = cmulf(t, make_float2(d.x*ib, -d.y*ib));
      }
      for (int c=0;c<4;c++) avec[c] = xv[c];
    }
    __syncthreads();
    if (valid) {
      #pragma unroll
      for (int c=0;c<NC;c++) {
        const size_t rb = ((size_t)(b*NC+c)*NF + f)*NFRM;
        float2 a = avec[c];
        float2 y0 = cmulf(a, x[c][0]), y1 = cmulf(a, x[c][1]);
        float2 y2 = cmulf(a, x[c][2]), y3 = cmulf(a, x[c][3]);
        *(float4*)(Xdr + rb + n0) = make_float4(y0.x,y1.x,y2.x,y3.x);
        *(float4*)(Xdi + rb + n0) = make_float4(y0.y,y1.y,y2.y,y3.y);
      }
    }
  } else {
    if (valid) {
      #pragma unroll
      for (int c=0;c<NC;c++) {
        const size_t rb = ((size_t)(b*NC+c)*NF + f)*NFRM;
        *(float4*)(Xdr + rb + n0) = make_float4(x[c][0].x,x[c][1].x,x[c][2].x,x[c][3].x);
        *(float4*)(Xdi + rb + n0) = make_float4(x[c][0].y,x[c][1].y,x[c][2].y,x[c][3].y);
      }
    }
    if (tid < 16) Wg[(size_t)(b*NF+f)*16 + tid] = Wl[tid>>2][tid&3];
  }
}

extern "C" void kernel_launch(void* const* d_in, const int* in_sizes, int n_in,
                              void* d_out, int out_size, void* d_ws, size_t ws_size,
                              hipStream_t stream)
{
  (void)in_sizes; (void)n_in; (void)out_size; (void)ws_size;
  const float* xr_in = (const float*)d_in[0];
  const float* xi_in = (const float*)d_in[1];
  float* outr = (float*)d_out;
  float* outi = outr + PLANE;

  char*  ws    = (char*)d_ws;
  float* rsum  = (float*)ws;                       // 32000 floats = 128 KB
  float* w0g   = (float*)(ws + 128000);            // 32000 floats = 128 KB
  float* gpart = (float*)(ws + 256000);            // 48 floats
  float2* Wg   = (float2*)(ws + 256000 + 256);     // 1028*16 float2 = 131,584 B

  dim3 grR(2, RFC, NB*NC);    // 928 blocks
  dim3 grU(NF, NB);           // 1028 blocks

  k_zero<<<126, 256, 0, stream>>>(rsum, gpart);

  // iteration 0 (X = original input)
  k_r<<<grR, 256, 0, stream>>>(xr_in, xi_in, rsum, gpart + 0);
  k_w<<<125, 256, 0, stream>>>(rsum, gpart + 0, w0g);
  k_u<true,false><<<grU, UT, 0, stream>>>(xr_in, xi_in, xr_in, xi_in,
                                          outr, outi, w0g, gpart + 0, Wg);
  // iteration 1
  k_r<<<grR, 256, 0, stream>>>(outr, outi, rsum, gpart + 16);
  k_w<<<125, 256, 0, stream>>>(rsum, gpart + 16, w0g);
  k_u<false,false><<<grU, UT, 0, stream>>>(outr, outi, xr_in, xi_in,
                                           outr, outi, w0g, gpart + 16, Wg);
  // iteration 2 + projection_back
  k_r<<<grR, 256, 0, stream>>>(outr, outi, rsum, gpart + 32);
  k_w<<<125, 256, 0, stream>>>(rsum, gpart + 32, w0g);
  k_u<false,true><<<grU, UT, 0, stream>>>(outr, outi, xr_in, xi_in,
                                          outr, outi, w0g, gpart + 32, Wg);
}